// Round 3
// baseline (1351.666 us; speedup 1.0000x reference)
//
#include <hip/hip_runtime.h>

// Problem constants: B=2, S=1024, D=512, H=8, L=6, V=32000, W=64, FF=2048, HD=64
// I/O dtype: float32 (per reference). Internal activations: bf16 (threshold 4.8e-2 allows it).
#define SEQ    1024
#define DIM    512
#define NHEAD  8
#define NLAYER 6
#define FFDIM  2048
#define HDIM   64
#define BATCH  2
#define VOCAB  32000
#define ROWS   (BATCH * SEQ)   // 2048 token rows

typedef __attribute__((ext_vector_type(8))) __bf16 bf16x8;
typedef __attribute__((ext_vector_type(4))) float  f32x4;

__device__ __forceinline__ unsigned short f2bf(float f) {
    unsigned int u = __float_as_uint(f);
    u += 0x7FFFu + ((u >> 16) & 1u);           // round-to-nearest-even
    return (unsigned short)(u >> 16);
}
__device__ __forceinline__ float bf2f(unsigned short u) {
    return __uint_as_float(((unsigned int)u) << 16);
}
__device__ __forceinline__ float lo_f(unsigned int u) { return __uint_as_float(u << 16); }
__device__ __forceinline__ float hi_f(unsigned int u) { return __uint_as_float(u & 0xFFFF0000u); }
__device__ __forceinline__ unsigned int pack2(float a, float b) {   // a -> low half
    return (unsigned int)f2bf(a) | ((unsigned int)f2bf(b) << 16);
}

// ---------------------------------------------------------------------------
// bf16 <- f32, 8 elements/thread. count must be a multiple of 2048.
// ---------------------------------------------------------------------------
__global__ __launch_bounds__(256) void cvt_kernel(const float* __restrict__ in,
                                                  unsigned short* __restrict__ out) {
    int base = (blockIdx.x * 256 + threadIdx.x) * 8;
    float4 a = *(const float4*)(in + base);
    float4 b = *(const float4*)(in + base + 4);
    *(uint4*)(out + base) = make_uint4(pack2(a.x, a.y), pack2(a.z, a.w),
                                       pack2(b.x, b.y), pack2(b.z, b.w));
}

// ---------------------------------------------------------------------------
// x[row, :] = bf16( emb_f32[ids[row], :] + sinusoidal_pos_enc(row % SEQ, :) )
// ---------------------------------------------------------------------------
__global__ __launch_bounds__(256) void embed_kernel(const int* __restrict__ ids,
                                                    const float* __restrict__ emb,
                                                    unsigned short* __restrict__ x) {
    int t8   = blockIdx.x * 256 + threadIdx.x;   // one thread = 8 elements
    int base = t8 * 8;
    int row  = base >> 9;        // / DIM
    int d0   = base & (DIM - 1);
    int s    = row & (SEQ - 1);
    int id   = ids[row];
    const float* er = emb + (size_t)id * DIM + d0;
    float4 ea = *(const float4*)(er);
    float4 eb = *(const float4*)(er + 4);
    float e[8] = {ea.x, ea.y, ea.z, ea.w, eb.x, eb.y, eb.z, eb.w};
    unsigned int ou[4];
#pragma unroll
    for (int m = 0; m < 4; ++m) {
        int de = d0 + 2 * m;                                     // even dim index
        float div = expf((float)de * -0.017988946039015984f);    // -ln(10000)/512
        float arg = (float)s * div;
        ou[m] = pack2(e[2 * m] + sinf(arg), e[2 * m + 1] + cosf(arg));
    }
    *(uint4*)(x + base) = make_uint4(ou[0], ou[1], ou[2], ou[3]);
}

// ---------------------------------------------------------------------------
// C[M,N] = A[M,K] @ W[N,K]^T (+ bias[N]); A and W both bf16 (weights are
// pre-converted), fp32 MFMA accum.
// MODE 0: C bf16 at row*N+col (intermediate activations)
// MODE 1: C f32  at row*N+col (lm head)
// MODE 2: QKV split: cols <1024 (Q|K) -> bf16 at row*1024+col; cols >=1024 (V)
//         -> TRANSPOSED bf16 vT[(col-1024)*ROWS + row] (packed 8B stores).
// Block: 256 thr (4 waves, 2x2), tile 128x128, BK=64, MFMA 16x16x32 bf16.
// Staging: __builtin_amdgcn_global_load_lds width=16 (m97 structure) -- LDS
// is LINEAR [128][64] (gload_lds dest = wave-uniform base + lane*16; no pad).
// Work order: row-tile fastest (M/128 == 16 always) + bijective XCD swizzle
// so the 16 row-tiles sharing one 128-col W panel run on the SAME XCD.
// ---------------------------------------------------------------------------
template <int MODE>
__global__ __launch_bounds__(256) void gemm_kernel(const unsigned short* __restrict__ A,
                                                   const unsigned short* __restrict__ W,
                                                   const float* __restrict__ bias,
                                                   void* __restrict__ Cout,
                                                   int M, int N, int K,
                                                   unsigned short* __restrict__ vT) {
    __shared__ __align__(16) unsigned short As[128 * 64];
    __shared__ __align__(16) unsigned short Bs[128 * 64];
    const int tid  = threadIdx.x;
    // --- XCD-aware swizzle: work id wk; row tile = wk & 15, col tile = wk >> 4
    const int nwg = (int)(gridDim.x * gridDim.y);          // multiple of 8 for all launches
    const int bid = (int)(blockIdx.y * gridDim.x + blockIdx.x);
    const int cpx = nwg >> 3;
    const int wk  = (bid & 7) * cpx + (bid >> 3);
    const int m0  = (wk & 15) * 128;                       // M == 2048 always
    const int n0  = (wk >> 4) * 128;
    const int lane = tid & 63;
    const int wv   = tid >> 6;
    const int wr   = wv >> 1, wc = wv & 1;       // wave's 64x64 quadrant
    const int frow = lane & 15, quad = lane >> 4;

    f32x4 acc[4][4] = {};

    // staging map: wave wv owns tile rows [wv*32, wv*32+32), 4 rounds of 8 rows.
    // per gload_lds instr: 64 lanes x 16B = 8 rows; lane -> (row=lane>>3, col8=lane&7)
    const int srow = wv * 32 + (lane >> 3);
    const int scol = (lane & 7) * 8;
    const unsigned short* Ag = A + (size_t)(m0 + srow) * K + scol;
    const unsigned short* Wg = W + (size_t)(n0 + srow) * K + scol;
    unsigned short* Asw = &As[(wv * 32) * 64];   // wave-uniform LDS bases
    unsigned short* Bsw = &Bs[(wv * 32) * 64];

    for (int k0 = 0; k0 < K; k0 += 64) {
#pragma unroll
        for (int p = 0; p < 4; ++p) {
            __builtin_amdgcn_global_load_lds(
                (const __attribute__((address_space(1))) void*)(Ag + (size_t)(p * 8) * K + k0),
                (__attribute__((address_space(3))) void*)(Asw + p * 8 * 64), 16, 0, 0);
            __builtin_amdgcn_global_load_lds(
                (const __attribute__((address_space(1))) void*)(Wg + (size_t)(p * 8) * K + k0),
                (__attribute__((address_space(3))) void*)(Bsw + p * 8 * 64), 16, 0, 0);
        }
        __syncthreads();   // compiler emits vmcnt(0) drain before barrier
#pragma unroll
        for (int kk = 0; kk < 64; kk += 32) {
            bf16x8 af[4], bfr[4];
#pragma unroll
            for (int t = 0; t < 4; ++t) {
                af[t]  = *(const bf16x8*)&As[(wr * 64 + t * 16 + frow) * 64 + kk + quad * 8];
                bfr[t] = *(const bf16x8*)&Bs[(wc * 64 + t * 16 + frow) * 64 + kk + quad * 8];
            }
#pragma unroll
            for (int am = 0; am < 4; ++am)
#pragma unroll
                for (int bn = 0; bn < 4; ++bn)
                    acc[am][bn] = __builtin_amdgcn_mfma_f32_16x16x32_bf16(af[am], bfr[bn], acc[am][bn], 0, 0, 0);
        }
        __syncthreads();
    }

    // epilogue: D row = (lane>>4)*4 + r, col = lane&15 (verified C/D layout)
#pragma unroll
    for (int am = 0; am < 4; ++am) {
#pragma unroll
        for (int bn = 0; bn < 4; ++bn) {
            int col  = n0 + wc * 64 + bn * 16 + frow;
            float bv = bias ? bias[col] : 0.0f;
            int rowb = m0 + wr * 64 + am * 16 + quad * 4;
            if (MODE == 2 && col >= 1024) {
                // V part, transposed: vT[feat][token], 4 consecutive tokens -> 8B store
                float v0 = acc[am][bn][0] + bv;
                float v1 = acc[am][bn][1] + bv;
                float v2 = acc[am][bn][2] + bv;
                float v3 = acc[am][bn][3] + bv;
                *(uint2*)&vT[(size_t)(col - 1024) * ROWS + rowb] =
                    make_uint2(pack2(v0, v1), pack2(v2, v3));
            } else {
#pragma unroll
                for (int r = 0; r < 4; ++r) {
                    int row = rowb + r;
                    float v = acc[am][bn][r] + bv;
                    if (MODE == 1)      ((float*)Cout)[(size_t)row * N + col] = v;
                    else if (MODE == 2) ((unsigned short*)Cout)[(size_t)row * 1024 + col] = f2bf(v);
                    else                ((unsigned short*)Cout)[(size_t)row * N + col] = f2bf(v);
                }
            }
        }
    }
}

// ---------------------------------------------------------------------------
// MFMA flash attention. One wave per (b, h, 16-query tile); wave = head.
// Grid: B * S/16 = 128 blocks x 512 threads (8 waves). win = (h+1)*64.
// qk layout: [token][1024] = q(512)|k(512) bf16. vT layout: [512][ROWS] bf16.
// ---------------------------------------------------------------------------
__global__ __launch_bounds__(512) void attn_kernel(const unsigned short* __restrict__ qk,
                                                   const unsigned short* __restrict__ vT,
                                                   unsigned short* __restrict__ out) {
    __shared__ __align__(16) unsigned short P_lds[8][16 * 40];
    const int tid  = threadIdx.x;
    const int w    = tid >> 6, lane = tid & 63;
    const int c    = lane & 15, g = lane >> 4;
    const int b    = blockIdx.x >> 6;
    const int qt   = blockIdx.x & 63;
    const int h    = w;
    const int qbase = qt * 16;
    const int win   = (h + 1) * 64;
    const int qmax  = qbase + 15;
    int kbs = qbase - win + 1; if (kbs < 0) kbs = 0; kbs &= ~31;

    const size_t tok0 = (size_t)b * SEQ;

    // Q fragments (held in registers all along): lane -> (q = c, hd = g*8..+8)
    const unsigned short* qp = qk + (tok0 + qbase + c) * 1024 + h * HDIM + g * 8;
    const bf16x8 qf0 = *(const bf16x8*)qp;          // hd 0..31 slice
    const bf16x8 qf1 = *(const bf16x8*)(qp + 32);   // hd 32..63 slice

    f32x4 o[4] = {};                                 // O acc: o[hd_tile][reg]
    float m[4]    = {-3.0e38f, -3.0e38f, -3.0e38f, -3.0e38f};
    float lsum[4] = {};

    unsigned short* pl = P_lds[w];

    for (int kb = kbs; kb <= qmax; kb += 32) {
        // ----- scores: S[16q][32k], two 16-key subtiles, K-dim = HD = 64 -----
        f32x4 s[2] = {};
#pragma unroll
        for (int st = 0; st < 2; ++st) {
            const unsigned short* kp = qk + (tok0 + kb + st * 16 + c) * 1024 + DIM + h * HDIM + g * 8;
            bf16x8 kf0 = *(const bf16x8*)kp;
            bf16x8 kf1 = *(const bf16x8*)(kp + 32);
            s[st] = __builtin_amdgcn_mfma_f32_16x16x32_bf16(qf0, kf0, s[st], 0, 0, 0);
            s[st] = __builtin_amdgcn_mfma_f32_16x16x32_bf16(qf1, kf1, s[st], 0, 0, 0);
        }
        // ----- mask + scale + row max (reduce over 16 lanes of the group) -----
        float sm[2][4];
        bool  va[2][4];
        float tmax[4];
#pragma unroll
        for (int r = 0; r < 4; ++r) {
            int i  = qbase + 4 * g + r;
            int j0 = kb + c, j1 = j0 + 16;
            bool v0 = (unsigned)(i - j0) < (unsigned)win;   // 0 <= i-j < win
            bool v1 = (unsigned)(i - j1) < (unsigned)win;
            va[0][r] = v0; va[1][r] = v1;
            sm[0][r] = v0 ? s[0][r] * 0.125f : -3.0e38f;
            sm[1][r] = v1 ? s[1][r] * 0.125f : -3.0e38f;
            float t = fmaxf(sm[0][r], sm[1][r]);
#pragma unroll
            for (int off = 1; off < 16; off <<= 1) t = fmaxf(t, __shfl_xor(t, off));
            tmax[r] = t;
        }
        // ----- online softmax update + write P (bf16) to LDS -----
#pragma unroll
        for (int r = 0; r < 4; ++r) {
            float mnew = fmaxf(m[r], tmax[r]);
            float scal = __expf(m[r] - mnew);               // 0 on first valid tile
            float p0 = va[0][r] ? __expf(sm[0][r] - mnew) : 0.0f;
            float p1 = va[1][r] ? __expf(sm[1][r] - mnew) : 0.0f;
            float rs = p0 + p1;
#pragma unroll
            for (int off = 1; off < 16; off <<= 1) rs += __shfl_xor(rs, off);
            lsum[r] = lsum[r] * scal + rs;
            m[r] = mnew;
#pragma unroll
            for (int t = 0; t < 4; ++t) o[t][r] *= scal;
            pl[(4 * g + r) * 40 + c]      = f2bf(p0);
            pl[(4 * g + r) * 40 + c + 16] = f2bf(p1);
        }
        // ----- PV: O[16q][64hd] += P[16q][32k] @ V[32k][64hd] -----
        bf16x8 pf = *(const bf16x8*)&pl[c * 40 + g * 8];
#pragma unroll
        for (int t = 0; t < 4; ++t) {
            const unsigned short* vp = vT + (size_t)(h * HDIM + t * 16 + c) * ROWS + tok0 + kb + g * 8;
            bf16x8 vf = *(const bf16x8*)vp;
            o[t] = __builtin_amdgcn_mfma_f32_16x16x32_bf16(pf, vf, o[t], 0, 0, 0);
        }
    }

    float inv[4];
#pragma unroll
    for (int r = 0; r < 4; ++r) inv[r] = 1.0f / lsum[r];
#pragma unroll
    for (int t = 0; t < 4; ++t)
#pragma unroll
        for (int r = 0; r < 4; ++r)
            out[(tok0 + qbase + 4 * g + r) * DIM + h * HDIM + t * 16 + c] = f2bf(o[t][r] * inv[r]);
}

// ---------------------------------------------------------------------------
// out = bf16( LayerNorm(x (+ res)) * g + b ) — biased variance, eps 1e-5.
// ---------------------------------------------------------------------------
__global__ __launch_bounds__(256) void ln_kernel(const unsigned short* __restrict__ xin,
                                                 const unsigned short* __restrict__ res,
                                                 const float* __restrict__ g,
                                                 const float* __restrict__ bta,
                                                 unsigned short* __restrict__ out) {
    const int tid = threadIdx.x;
    const int w   = tid >> 6, lane = tid & 63;
    const int row = blockIdx.x * 4 + w;
    const int c0  = lane * 8;
    const size_t base = (size_t)row * DIM + c0;

    uint4 xv = *(const uint4*)(xin + base);
    float v[8] = {lo_f(xv.x), hi_f(xv.x), lo_f(xv.y), hi_f(xv.y),
                  lo_f(xv.z), hi_f(xv.z), lo_f(xv.w), hi_f(xv.w)};
    if (res) {
        uint4 rv = *(const uint4*)(res + base);
        v[0] += lo_f(rv.x); v[1] += hi_f(rv.x); v[2] += lo_f(rv.y); v[3] += hi_f(rv.y);
        v[4] += lo_f(rv.z); v[5] += hi_f(rv.z); v[6] += lo_f(rv.w); v[7] += hi_f(rv.w);
    }
    float sum = 0.0f, sq = 0.0f;
#pragma unroll
    for (int t = 0; t < 8; ++t) { sum += v[t]; sq += v[t] * v[t]; }
#pragma unroll
    for (int off = 32; off >= 1; off >>= 1) { sum += __shfl_xor(sum, off); sq += __shfl_xor(sq, off); }
    float mean = sum * (1.0f / DIM);
    float var  = sq * (1.0f / DIM) - mean * mean;
    float rstd = rsqrtf(var + 1e-5f);

    float4 ga = *(const float4*)(g + c0);
    float4 gb = *(const float4*)(g + c0 + 4);
    float4 ba = *(const float4*)(bta + c0);
    float4 bb = *(const float4*)(bta + c0 + 4);
    float gf[8] = {ga.x, ga.y, ga.z, ga.w, gb.x, gb.y, gb.z, gb.w};
    float bf[8] = {ba.x, ba.y, ba.z, ba.w, bb.x, bb.y, bb.z, bb.w};
    unsigned int o[4];
#pragma unroll
    for (int mm = 0; mm < 4; ++mm) {
        float a0 = (v[2 * mm]     - mean) * rstd * gf[2 * mm]     + bf[2 * mm];
        float a1 = (v[2 * mm + 1] - mean) * rstd * gf[2 * mm + 1] + bf[2 * mm + 1];
        o[mm] = pack2(a0, a1);
    }
    *(uint4*)(out + base) = make_uint4(o[0], o[1], o[2], o[3]);
}

// ---------------------------------------------------------------------------
// SwiGLU: h[M, 4096] bf16 -> o[M, 2048] bf16; o = h[:, :2048] * silu(h[:, 2048:])
// ---------------------------------------------------------------------------
__global__ __launch_bounds__(256) void swiglu_kernel(const unsigned short* __restrict__ h,
                                                     unsigned short* __restrict__ o) {
    int t8   = blockIdx.x * 256 + threadIdx.x;
    int base = t8 * 8;
    int r = base >> 11;           // / FFDIM
    int c = base & (FFDIM - 1);
    const unsigned short* hr = h + (size_t)r * (2 * FFDIM);
    uint4 uv = *(const uint4*)(hr + c);
    uint4 gv = *(const uint4*)(hr + FFDIM + c);
    float u[8] = {lo_f(uv.x), hi_f(uv.x), lo_f(uv.y), hi_f(uv.y),
                  lo_f(uv.z), hi_f(uv.z), lo_f(uv.w), hi_f(uv.w)};
    float gg[8] = {lo_f(gv.x), hi_f(gv.x), lo_f(gv.y), hi_f(gv.y),
                   lo_f(gv.z), hi_f(gv.z), lo_f(gv.w), hi_f(gv.w)};
    unsigned int ov[4];
#pragma unroll
    for (int m = 0; m < 4; ++m) {
        float g0 = gg[2 * m],     s0 = g0 / (1.0f + expf(-g0));
        float g1 = gg[2 * m + 1], s1 = g1 / (1.0f + expf(-g1));
        ov[m] = pack2(u[2 * m] * s0, u[2 * m + 1] * s1);
    }
    *(uint4*)(o + (size_t)r * FFDIM + c) = make_uint4(ov[0], ov[1], ov[2], ov[3]);
}

// ---------------------------------------------------------------------------
extern "C" void kernel_launch(void* const* d_in, const int* in_sizes, int n_in,
                              void* d_out, int out_size, void* d_ws, size_t ws_size,
                              hipStream_t stream) {
    const int*   ids  = (const int*)d_in[0];
    const float* emb  = (const float*)d_in[1];
    const float* Wqkv = (const float*)d_in[2];
    const float* bqkv = (const float*)d_in[3];
    const float* Wo   = (const float*)d_in[4];
    const float* bo   = (const float*)d_in[5];
    const float* W1   = (const float*)d_in[6];
    const float* b1   = (const float*)d_in[7];
    const float* W2   = (const float*)d_in[8];
    const float* b2   = (const float*)d_in[9];
    const float* ln1g = (const float*)d_in[10];
    const float* ln1b = (const float*)d_in[11];
    const float* ln2g = (const float*)d_in[12];
    const float* ln2b = (const float*)d_in[13];
    const float* lnfg = (const float*)d_in[14];
    const float* lnfb = (const float*)d_in[15];

    unsigned short* x    = (unsigned short*)d_ws;            // [2048, 512]  bf16, 2 MB
    unsigned short* qk   = x    + (size_t)ROWS * DIM;        // [2048, 1024] (q|k)
    unsigned short* vT   = qk   + (size_t)ROWS * 2 * DIM;    // [512, 2048]  V transposed
    unsigned short* attn = vT   + (size_t)DIM * ROWS;        // [2048, 512]
    unsigned short* proj = attn + (size_t)ROWS * DIM;        // [2048, 512]
    unsigned short* hbuf = proj + (size_t)ROWS * DIM;        // [2048, 4096]
    unsigned short* ffin = hbuf + (size_t)ROWS * 2 * FFDIM;  // [2048, 2048]
    // all-layer bf16 weights (converted once up front; ws ~1 GB, plenty)
    unsigned short* WqkvB = ffin + (size_t)ROWS * FFDIM;     // [L, 1536, 512]
    unsigned short* WoB   = WqkvB + (size_t)NLAYER * 3 * DIM * DIM;   // [L, 512, 512]
    unsigned short* W1B   = WoB   + (size_t)NLAYER * DIM * DIM;       // [L, 4096, 512]
    unsigned short* W2B   = W1B   + (size_t)NLAYER * 2 * FFDIM * DIM; // [L, 512, 2048]
    unsigned short* embB  = W2B   + (size_t)NLAYER * DIM * FFDIM;     // [32000, 512]
    // total ws high-water: ~120 MB

    // one cvt launch per tensor family (layers are contiguous) + emb
    cvt_kernel<<<NLAYER * 3 * DIM * DIM / 2048, 256, 0, stream>>>(Wqkv, WqkvB);
    cvt_kernel<<<NLAYER * DIM * DIM / 2048, 256, 0, stream>>>(Wo, WoB);
    cvt_kernel<<<NLAYER * 2 * FFDIM * DIM / 2048, 256, 0, stream>>>(W1, W1B);
    cvt_kernel<<<NLAYER * DIM * FFDIM / 2048, 256, 0, stream>>>(W2, W2B);
    cvt_kernel<<<VOCAB * DIM / 2048, 256, 0, stream>>>(emb, embB);

    embed_kernel<<<ROWS * DIM / (256 * 8), 256, 0, stream>>>(ids, emb, x);

    for (int l = 0; l < NLAYER; ++l) {
        gemm_kernel<2><<<dim3(16, 12), 256, 0, stream>>>(x, WqkvB + (size_t)l * 3 * DIM * DIM,
                                                         bqkv + l * 3 * DIM, qk, ROWS, 3 * DIM, DIM, vT);
        attn_kernel<<<BATCH * (SEQ / 16), 512, 0, stream>>>(qk, vT, attn);
        gemm_kernel<0><<<dim3(16, 4), 256, 0, stream>>>(attn, WoB + (size_t)l * DIM * DIM,
                                                        bo + l * DIM, proj, ROWS, DIM, DIM, nullptr);
        ln_kernel<<<ROWS / 4, 256, 0, stream>>>(x, proj, ln1g + l * DIM, ln1b + l * DIM, x);
        gemm_kernel<0><<<dim3(16, 32), 256, 0, stream>>>(x, W1B + (size_t)l * 2 * FFDIM * DIM,
                                                         b1 + l * 2 * FFDIM, hbuf, ROWS, 2 * FFDIM, DIM, nullptr);
        swiglu_kernel<<<ROWS * FFDIM / (256 * 8), 256, 0, stream>>>(hbuf, ffin);
        gemm_kernel<0><<<dim3(16, 4), 256, 0, stream>>>(ffin, W2B + (size_t)l * DIM * FFDIM,
                                                        b2 + l * DIM, attn /*ffout*/, ROWS, DIM, FFDIM, nullptr);
        ln_kernel<<<ROWS / 4, 256, 0, stream>>>(x, attn, ln2g + l * DIM, ln2b + l * DIM, x);
    }
    ln_kernel<<<ROWS / 4, 256, 0, stream>>>(x, nullptr, lnfg, lnfb, x);
    gemm_kernel<1><<<dim3(16, VOCAB / 128), 256, 0, stream>>>(x, embB, nullptr,
                                                              d_out, ROWS, VOCAB, DIM, nullptr);
}

// Round 4
// 1189.534 us; speedup vs baseline: 1.1363x; 1.1363x over previous
//
#include <hip/hip_runtime.h>

// Problem constants: B=2, S=1024, D=512, H=8, L=6, V=32000, W=64, FF=2048, HD=64
// I/O dtype: float32 (per reference). Internal activations: bf16 (threshold 4.8e-2 allows it).
#define SEQ    1024
#define DIM    512
#define NHEAD  8
#define NLAYER 6
#define FFDIM  2048
#define HDIM   64
#define BATCH  2
#define VOCAB  32000
#define ROWS   (BATCH * SEQ)   // 2048 token rows

typedef __attribute__((ext_vector_type(8))) __bf16 bf16x8;
typedef __attribute__((ext_vector_type(4))) float  f32x4;

__device__ __forceinline__ unsigned short f2bf(float f) {
    unsigned int u = __float_as_uint(f);
    u += 0x7FFFu + ((u >> 16) & 1u);           // round-to-nearest-even
    return (unsigned short)(u >> 16);
}
__device__ __forceinline__ float bf2f(unsigned short u) {
    return __uint_as_float(((unsigned int)u) << 16);
}
__device__ __forceinline__ float lo_f(unsigned int u) { return __uint_as_float(u << 16); }
__device__ __forceinline__ float hi_f(unsigned int u) { return __uint_as_float(u & 0xFFFF0000u); }
__device__ __forceinline__ unsigned int pack2(float a, float b) {   // a -> low half
    return (unsigned int)f2bf(a) | ((unsigned int)f2bf(b) << 16);
}

// ---------------------------------------------------------------------------
// bf16 <- f32, 8 elements/thread. count must be a multiple of 2048.
// ---------------------------------------------------------------------------
__global__ __launch_bounds__(256) void cvt_kernel(const float* __restrict__ in,
                                                  unsigned short* __restrict__ out) {
    int base = (blockIdx.x * 256 + threadIdx.x) * 8;
    float4 a = *(const float4*)(in + base);
    float4 b = *(const float4*)(in + base + 4);
    *(uint4*)(out + base) = make_uint4(pack2(a.x, a.y), pack2(a.z, a.w),
                                       pack2(b.x, b.y), pack2(b.z, b.w));
}

// ---------------------------------------------------------------------------
// x[row, :] = bf16( emb_f32[ids[row], :] + sinusoidal_pos_enc(row % SEQ, :) )
// ---------------------------------------------------------------------------
__global__ __launch_bounds__(256) void embed_kernel(const int* __restrict__ ids,
                                                    const float* __restrict__ emb,
                                                    unsigned short* __restrict__ x) {
    int t8   = blockIdx.x * 256 + threadIdx.x;   // one thread = 8 elements
    int base = t8 * 8;
    int row  = base >> 9;        // / DIM
    int d0   = base & (DIM - 1);
    int s    = row & (SEQ - 1);
    int id   = ids[row];
    const float* er = emb + (size_t)id * DIM + d0;
    float4 ea = *(const float4*)(er);
    float4 eb = *(const float4*)(er + 4);
    float e[8] = {ea.x, ea.y, ea.z, ea.w, eb.x, eb.y, eb.z, eb.w};
    unsigned int ou[4];
#pragma unroll
    for (int m = 0; m < 4; ++m) {
        int de = d0 + 2 * m;                                     // even dim index
        float div = expf((float)de * -0.017988946039015984f);    // -ln(10000)/512
        float arg = (float)s * div;
        ou[m] = pack2(e[2 * m] + sinf(arg), e[2 * m + 1] + cosf(arg));
    }
    *(uint4*)(x + base) = make_uint4(ou[0], ou[1], ou[2], ou[3]);
}

// ---------------------------------------------------------------------------
// C[M,N] = A[M,K] @ W[N,K]^T (+ bias[N]); A and W both bf16 (pre-converted),
// fp32 MFMA accum. Tile 128 x (128*NT), BK=64, MFMA 16x16x32, 256 thr (2x2 waves).
// MODE 0 (NT=1): C bf16 at row*N+col
// MODE 1 (NT=2): C f32  at row*N+col (lm head, 256-wide tiles)
// MODE 2 (NT=1): QKV split: cols <1024 -> bf16 row*1024+col; V -> vT transposed
// MODE 3 (NT=2): W1+SwiGLU fused: panel0 = W1 rows [n0,n0+128) (u),
//                panel1 = W1 rows [FF+n0, FF+n0+128) (g);
//                writes bf16 ffin[row*N + n0+col] = u * silu(g).
// Staging: global_load_lds width=16, LINEAR LDS dest + XOR-swizzle (rule #21):
//   source col pre-swizzled (gb_src = (lane&7)^(lane>>3)), read col XORed with
//   row&7 -> 2-way banks (free) instead of 16-way on ds_read_b128.
// Work order: row-tile fastest + bijective XCD swizzle (all grids mult of 8).
// ---------------------------------------------------------------------------
template <int MODE, int NT>
__global__ __launch_bounds__(256, 2) void gemm_kernel(const unsigned short* __restrict__ A,
                                                      const unsigned short* __restrict__ W,
                                                      const float* __restrict__ bias,
                                                      void* __restrict__ Cout,
                                                      int M, int N, int K,
                                                      unsigned short* __restrict__ vT) {
    __shared__ __align__(16) unsigned short As[128 * 64];
    __shared__ __align__(16) unsigned short Bs[NT * 128 * 64];
    const int tid  = threadIdx.x;
    const int nwg = (int)(gridDim.x * gridDim.y);          // multiple of 8 for all launches
    const int bid = (int)(blockIdx.y * gridDim.x + blockIdx.x);
    const int cpx = nwg >> 3;
    const int wk  = (bid & 7) * cpx + (bid >> 3);
    const int m0  = (wk & 15) * 128;                       // M == 2048 always
    const int ct  = wk >> 4;
    const int n0  = (MODE == 1) ? ct * 256 : ct * 128;     // col base (NT=2 lm: 256-wide)
    const int lane = tid & 63;
    const int wv   = tid >> 6;
    const int wr   = wv >> 1, wc = wv & 1;       // wave's 64x64 quadrant (per panel)
    const int frow = lane & 15, quad = lane >> 4;

    f32x4 acc[4][4 * NT] = {};

    // staging: lane -> row offset lane>>3 (0..7), source 16B-group pre-swizzled
    const int lrow = lane >> 3;
    const int scol = ((lane & 7) ^ lrow) * 8;              // XOR source swizzle
    const unsigned short* Ag = A + (size_t)(m0 + wv * 32 + lrow) * K + scol;
    unsigned short* Asw = &As[(wv * 32) * 64];             // wave-uniform LDS base

    for (int k0 = 0; k0 < K; k0 += 64) {
#pragma unroll
        for (int p = 0; p < 4; ++p) {
            __builtin_amdgcn_global_load_lds(
                (const __attribute__((address_space(1))) void*)(Ag + (size_t)(p * 8) * K + k0),
                (__attribute__((address_space(3))) void*)(Asw + p * 8 * 64), 16, 0, 0);
        }
        if (NT == 1) {
            const unsigned short* Wg = W + (size_t)(n0 + wv * 32 + lrow) * K + scol;
#pragma unroll
            for (int p = 0; p < 4; ++p) {
                __builtin_amdgcn_global_load_lds(
                    (const __attribute__((address_space(1))) void*)(Wg + (size_t)(p * 8) * K + k0),
                    (__attribute__((address_space(3))) void*)(&Bs[(wv * 32 + p * 8) * 64]), 16, 0, 0);
            }
        } else {
#pragma unroll
            for (int q = 0; q < 8; ++q) {
                int rl = wv * 64 + q * 8;                  // wave-uniform local B row
                int grow = (MODE == 3) ? (n0 + (rl & 127) + (rl >> 7) * FFDIM)
                                       : (n0 + rl);
                const unsigned short* src = W + (size_t)(grow + lrow) * K + scol + k0;
                __builtin_amdgcn_global_load_lds(
                    (const __attribute__((address_space(1))) void*)src,
                    (__attribute__((address_space(3))) void*)(&Bs[rl * 64]), 16, 0, 0);
            }
        }
        __syncthreads();   // compiler emits vmcnt(0) drain before barrier
#pragma unroll
        for (int kk = 0; kk < 64; kk += 32) {
            const int gsw = ((kk >> 3) + quad) ^ (frow & 7);   // swizzled 16B group
            bf16x8 af[4], bfr[4 * NT];
#pragma unroll
            for (int t = 0; t < 4; ++t)
                af[t] = *(const bf16x8*)&As[(wr * 64 + t * 16 + frow) * 64 + gsw * 8];
#pragma unroll
            for (int t = 0; t < 4 * NT; ++t) {
                int brow = (t >> 2) * 128 + wc * 64 + (t & 3) * 16 + frow;
                bfr[t] = *(const bf16x8*)&Bs[brow * 64 + gsw * 8];
            }
#pragma unroll
            for (int am = 0; am < 4; ++am)
#pragma unroll
                for (int bn = 0; bn < 4 * NT; ++bn)
                    acc[am][bn] = __builtin_amdgcn_mfma_f32_16x16x32_bf16(af[am], bfr[bn], acc[am][bn], 0, 0, 0);
        }
        __syncthreads();
    }

    // epilogue: D row = (lane>>4)*4 + r, col = lane&15 (verified C/D layout)
#pragma unroll
    for (int am = 0; am < 4; ++am) {
        int rowb = m0 + wr * 64 + am * 16 + quad * 4;
        if (MODE == 3) {
            // fused SwiGLU: u = panel0 (bn), g = panel1 (bn+4)
#pragma unroll
            for (int bn = 0; bn < 4; ++bn) {
                int colL = wc * 64 + bn * 16 + frow;
                float bu = bias[n0 + colL];
                float bg = bias[FFDIM + n0 + colL];
#pragma unroll
                for (int r = 0; r < 4; ++r) {
                    float u = acc[am][bn][r] + bu;
                    float g = acc[am][bn + 4][r] + bg;
                    float s = g / (1.0f + expf(-g));
                    ((unsigned short*)Cout)[(size_t)(rowb + r) * N + n0 + colL] = f2bf(u * s);
                }
            }
        } else {
#pragma unroll
            for (int bn = 0; bn < 4 * NT; ++bn) {
                int col = n0 + (bn >> 2) * 128 + wc * 64 + (bn & 3) * 16 + frow;
                float bv = bias ? bias[col] : 0.0f;
                if (MODE == 2 && col >= 1024) {
                    // V part, transposed: vT[feat][token], 4 tokens -> 8B store
                    float v0 = acc[am][bn][0] + bv;
                    float v1 = acc[am][bn][1] + bv;
                    float v2 = acc[am][bn][2] + bv;
                    float v3 = acc[am][bn][3] + bv;
                    *(uint2*)&vT[(size_t)(col - 1024) * ROWS + rowb] =
                        make_uint2(pack2(v0, v1), pack2(v2, v3));
                } else {
#pragma unroll
                    for (int r = 0; r < 4; ++r) {
                        float v = acc[am][bn][r] + bv;
                        if (MODE == 1)      ((float*)Cout)[(size_t)(rowb + r) * N + col] = v;
                        else if (MODE == 2) ((unsigned short*)Cout)[(size_t)(rowb + r) * 1024 + col] = f2bf(v);
                        else                ((unsigned short*)Cout)[(size_t)(rowb + r) * N + col] = f2bf(v);
                    }
                }
            }
        }
    }
}

// ---------------------------------------------------------------------------
// MFMA flash attention. One wave per (b, h, 16-query tile); wave = head.
// Grid: B * S/16 = 128 blocks x 512 threads (8 waves). win = (h+1)*64.
// qk layout: [token][1024] = q(512)|k(512) bf16. vT layout: [512][ROWS] bf16.
// ---------------------------------------------------------------------------
__global__ __launch_bounds__(512) void attn_kernel(const unsigned short* __restrict__ qk,
                                                   const unsigned short* __restrict__ vT,
                                                   unsigned short* __restrict__ out) {
    __shared__ __align__(16) unsigned short P_lds[8][16 * 40];
    const int tid  = threadIdx.x;
    const int w    = tid >> 6, lane = tid & 63;
    const int c    = lane & 15, g = lane >> 4;
    const int b    = blockIdx.x >> 6;
    const int qt   = blockIdx.x & 63;
    const int h    = w;
    const int qbase = qt * 16;
    const int win   = (h + 1) * 64;
    const int qmax  = qbase + 15;
    int kbs = qbase - win + 1; if (kbs < 0) kbs = 0; kbs &= ~31;

    const size_t tok0 = (size_t)b * SEQ;

    // Q fragments (held in registers all along): lane -> (q = c, hd = g*8..+8)
    const unsigned short* qp = qk + (tok0 + qbase + c) * 1024 + h * HDIM + g * 8;
    const bf16x8 qf0 = *(const bf16x8*)qp;          // hd 0..31 slice
    const bf16x8 qf1 = *(const bf16x8*)(qp + 32);   // hd 32..63 slice

    f32x4 o[4] = {};                                 // O acc: o[hd_tile][reg]
    float m[4]    = {-3.0e38f, -3.0e38f, -3.0e38f, -3.0e38f};
    float lsum[4] = {};

    unsigned short* pl = P_lds[w];

    for (int kb = kbs; kb <= qmax; kb += 32) {
        // ----- scores: S[16q][32k], two 16-key subtiles, K-dim = HD = 64 -----
        f32x4 s[2] = {};
#pragma unroll
        for (int st = 0; st < 2; ++st) {
            const unsigned short* kp = qk + (tok0 + kb + st * 16 + c) * 1024 + DIM + h * HDIM + g * 8;
            bf16x8 kf0 = *(const bf16x8*)kp;
            bf16x8 kf1 = *(const bf16x8*)(kp + 32);
            s[st] = __builtin_amdgcn_mfma_f32_16x16x32_bf16(qf0, kf0, s[st], 0, 0, 0);
            s[st] = __builtin_amdgcn_mfma_f32_16x16x32_bf16(qf1, kf1, s[st], 0, 0, 0);
        }
        // ----- mask + scale + row max (reduce over 16 lanes of the group) -----
        float sm[2][4];
        bool  va[2][4];
        float tmax[4];
#pragma unroll
        for (int r = 0; r < 4; ++r) {
            int i  = qbase + 4 * g + r;
            int j0 = kb + c, j1 = j0 + 16;
            bool v0 = (unsigned)(i - j0) < (unsigned)win;   // 0 <= i-j < win
            bool v1 = (unsigned)(i - j1) < (unsigned)win;
            va[0][r] = v0; va[1][r] = v1;
            sm[0][r] = v0 ? s[0][r] * 0.125f : -3.0e38f;
            sm[1][r] = v1 ? s[1][r] * 0.125f : -3.0e38f;
            float t = fmaxf(sm[0][r], sm[1][r]);
#pragma unroll
            for (int off = 1; off < 16; off <<= 1) t = fmaxf(t, __shfl_xor(t, off));
            tmax[r] = t;
        }
        // ----- online softmax update + write P (bf16) to LDS -----
#pragma unroll
        for (int r = 0; r < 4; ++r) {
            float mnew = fmaxf(m[r], tmax[r]);
            float scal = __expf(m[r] - mnew);               // 0 on first valid tile
            float p0 = va[0][r] ? __expf(sm[0][r] - mnew) : 0.0f;
            float p1 = va[1][r] ? __expf(sm[1][r] - mnew) : 0.0f;
            float rs = p0 + p1;
#pragma unroll
            for (int off = 1; off < 16; off <<= 1) rs += __shfl_xor(rs, off);
            lsum[r] = lsum[r] * scal + rs;
            m[r] = mnew;
#pragma unroll
            for (int t = 0; t < 4; ++t) o[t][r] *= scal;
            pl[(4 * g + r) * 40 + c]      = f2bf(p0);
            pl[(4 * g + r) * 40 + c + 16] = f2bf(p1);
        }
        // ----- PV: O[16q][64hd] += P[16q][32k] @ V[32k][64hd] -----
        bf16x8 pf = *(const bf16x8*)&pl[c * 40 + g * 8];
#pragma unroll
        for (int t = 0; t < 4; ++t) {
            const unsigned short* vp = vT + (size_t)(h * HDIM + t * 16 + c) * ROWS + tok0 + kb + g * 8;
            bf16x8 vf = *(const bf16x8*)vp;
            o[t] = __builtin_amdgcn_mfma_f32_16x16x32_bf16(pf, vf, o[t], 0, 0, 0);
        }
    }

    float inv[4];
#pragma unroll
    for (int r = 0; r < 4; ++r) inv[r] = 1.0f / lsum[r];
#pragma unroll
    for (int t = 0; t < 4; ++t)
#pragma unroll
        for (int r = 0; r < 4; ++r)
            out[(tok0 + qbase + 4 * g + r) * DIM + h * HDIM + t * 16 + c] = f2bf(o[t][r] * inv[r]);
}

// ---------------------------------------------------------------------------
// out = bf16( LayerNorm(x (+ res)) * g + b ) — biased variance, eps 1e-5.
// ---------------------------------------------------------------------------
__global__ __launch_bounds__(256) void ln_kernel(const unsigned short* __restrict__ xin,
                                                 const unsigned short* __restrict__ res,
                                                 const float* __restrict__ g,
                                                 const float* __restrict__ bta,
                                                 unsigned short* __restrict__ out) {
    const int tid = threadIdx.x;
    const int w   = tid >> 6, lane = tid & 63;
    const int row = blockIdx.x * 4 + w;
    const int c0  = lane * 8;
    const size_t base = (size_t)row * DIM + c0;

    uint4 xv = *(const uint4*)(xin + base);
    float v[8] = {lo_f(xv.x), hi_f(xv.x), lo_f(xv.y), hi_f(xv.y),
                  lo_f(xv.z), hi_f(xv.z), lo_f(xv.w), hi_f(xv.w)};
    if (res) {
        uint4 rv = *(const uint4*)(res + base);
        v[0] += lo_f(rv.x); v[1] += hi_f(rv.x); v[2] += lo_f(rv.y); v[3] += hi_f(rv.y);
        v[4] += lo_f(rv.z); v[5] += hi_f(rv.z); v[6] += lo_f(rv.w); v[7] += hi_f(rv.w);
    }
    float sum = 0.0f, sq = 0.0f;
#pragma unroll
    for (int t = 0; t < 8; ++t) { sum += v[t]; sq += v[t] * v[t]; }
#pragma unroll
    for (int off = 32; off >= 1; off >>= 1) { sum += __shfl_xor(sum, off); sq += __shfl_xor(sq, off); }
    float mean = sum * (1.0f / DIM);
    float var  = sq * (1.0f / DIM) - mean * mean;
    float rstd = rsqrtf(var + 1e-5f);

    float4 ga = *(const float4*)(g + c0);
    float4 gb = *(const float4*)(g + c0 + 4);
    float4 ba = *(const float4*)(bta + c0);
    float4 bb = *(const float4*)(bta + c0 + 4);
    float gf[8] = {ga.x, ga.y, ga.z, ga.w, gb.x, gb.y, gb.z, gb.w};
    float bf[8] = {ba.x, ba.y, ba.z, ba.w, bb.x, bb.y, bb.z, bb.w};
    unsigned int o[4];
#pragma unroll
    for (int mm = 0; mm < 4; ++mm) {
        float a0 = (v[2 * mm]     - mean) * rstd * gf[2 * mm]     + bf[2 * mm];
        float a1 = (v[2 * mm + 1] - mean) * rstd * gf[2 * mm + 1] + bf[2 * mm + 1];
        o[mm] = pack2(a0, a1);
    }
    *(uint4*)(out + base) = make_uint4(o[0], o[1], o[2], o[3]);
}

// ---------------------------------------------------------------------------
extern "C" void kernel_launch(void* const* d_in, const int* in_sizes, int n_in,
                              void* d_out, int out_size, void* d_ws, size_t ws_size,
                              hipStream_t stream) {
    const int*   ids  = (const int*)d_in[0];
    const float* emb  = (const float*)d_in[1];
    const float* Wqkv = (const float*)d_in[2];
    const float* bqkv = (const float*)d_in[3];
    const float* Wo   = (const float*)d_in[4];
    const float* bo   = (const float*)d_in[5];
    const float* W1   = (const float*)d_in[6];
    const float* b1   = (const float*)d_in[7];
    const float* W2   = (const float*)d_in[8];
    const float* b2   = (const float*)d_in[9];
    const float* ln1g = (const float*)d_in[10];
    const float* ln1b = (const float*)d_in[11];
    const float* ln2g = (const float*)d_in[12];
    const float* ln2b = (const float*)d_in[13];
    const float* lnfg = (const float*)d_in[14];
    const float* lnfb = (const float*)d_in[15];

    unsigned short* x    = (unsigned short*)d_ws;            // [2048, 512]  bf16, 2 MB
    unsigned short* qk   = x    + (size_t)ROWS * DIM;        // [2048, 1024] (q|k)
    unsigned short* vT   = qk   + (size_t)ROWS * 2 * DIM;    // [512, 2048]  V transposed
    unsigned short* attn = vT   + (size_t)DIM * ROWS;        // [2048, 512]
    unsigned short* proj = attn + (size_t)ROWS * DIM;        // [2048, 512]
    unsigned short* ffin = proj + (size_t)ROWS * DIM;        // [2048, 2048]
    // all-layer bf16 weights (converted once up front; ws ~1 GB, plenty)
    unsigned short* WqkvB = ffin + (size_t)ROWS * FFDIM;     // [L, 1536, 512]
    unsigned short* WoB   = WqkvB + (size_t)NLAYER * 3 * DIM * DIM;   // [L, 512, 512]
    unsigned short* W1B   = WoB   + (size_t)NLAYER * DIM * DIM;       // [L, 4096, 512]
    unsigned short* W2B   = W1B   + (size_t)NLAYER * 2 * FFDIM * DIM; // [L, 512, 2048]
    unsigned short* embB  = W2B   + (size_t)NLAYER * DIM * FFDIM;     // [32000, 512]
    // total ws high-water: ~110 MB

    // one cvt launch per tensor family (layers are contiguous) + emb
    cvt_kernel<<<NLAYER * 3 * DIM * DIM / 2048, 256, 0, stream>>>(Wqkv, WqkvB);
    cvt_kernel<<<NLAYER * DIM * DIM / 2048, 256, 0, stream>>>(Wo, WoB);
    cvt_kernel<<<NLAYER * 2 * FFDIM * DIM / 2048, 256, 0, stream>>>(W1, W1B);
    cvt_kernel<<<NLAYER * DIM * FFDIM / 2048, 256, 0, stream>>>(W2, W2B);
    cvt_kernel<<<VOCAB * DIM / 2048, 256, 0, stream>>>(emb, embB);

    embed_kernel<<<ROWS * DIM / (256 * 8), 256, 0, stream>>>(ids, emb, x);

    for (int l = 0; l < NLAYER; ++l) {
        gemm_kernel<2, 1><<<dim3(16, 12), 256, 0, stream>>>(x, WqkvB + (size_t)l * 3 * DIM * DIM,
                                                            bqkv + l * 3 * DIM, qk, ROWS, 3 * DIM, DIM, vT);
        attn_kernel<<<BATCH * (SEQ / 16), 512, 0, stream>>>(qk, vT, attn);
        gemm_kernel<0, 1><<<dim3(16, 4), 256, 0, stream>>>(attn, WoB + (size_t)l * DIM * DIM,
                                                           bo + l * DIM, proj, ROWS, DIM, DIM, nullptr);
        ln_kernel<<<ROWS / 4, 256, 0, stream>>>(x, proj, ln1g + l * DIM, ln1b + l * DIM, x);
        // fused W1 + SwiGLU: 16x16 grid, each block computes u & g panels
        gemm_kernel<3, 2><<<dim3(16, FFDIM / 128), 256, 0, stream>>>(x, W1B + (size_t)l * 2 * FFDIM * DIM,
                                                                     b1 + l * 2 * FFDIM, ffin, ROWS, FFDIM, DIM, nullptr);
        gemm_kernel<0, 1><<<dim3(16, 4), 256, 0, stream>>>(ffin, W2B + (size_t)l * DIM * FFDIM,
                                                           b2 + l * DIM, attn /*ffout*/, ROWS, DIM, FFDIM, nullptr);
        ln_kernel<<<ROWS / 4, 256, 0, stream>>>(x, attn, ln2g + l * DIM, ln2b + l * DIM, x);
    }
    ln_kernel<<<ROWS / 4, 256, 0, stream>>>(x, nullptr, lnfg, lnfb, x);
    gemm_kernel<1, 2><<<dim3(16, VOCAB / 256), 256, 0, stream>>>(x, embB, nullptr,
                                                                 d_out, ROWS, VOCAB, DIM, nullptr);
}